// Round 3
// baseline (339.889 us; speedup 1.0000x reference)
//
#include <hip/hip_runtime.h>
#include <hip/hip_bf16.h>

using bf16 = __hip_bfloat16;
typedef __attribute__((ext_vector_type(8))) short short8;   // 8 bf16 = 4 VGPRs (MFMA A/B frag)
typedef __attribute__((ext_vector_type(4))) float floatx4;  // MFMA C/D frag

#define NPc 4096
#define NCc 1024
#define Dc  512
#define Bc  4

// ---------------------------------------------------------------------------
// async global->LDS, 16B per lane. LDS dest = (wave-uniform base) + lane*16B.
// ---------------------------------------------------------------------------
__device__ __forceinline__ void async_copy16(const bf16* g, bf16* l) {
    __builtin_amdgcn_global_load_lds(
        (const __attribute__((address_space(1))) unsigned int*)g,
        (__attribute__((address_space(3))) unsigned int*)l,
        16, 0, 0);
}

// ---------------------------------------------------------------------------
// C[M x N] = scale * A[M x K] (row-major bf16) * Bt[N x K]^T (row-major bf16)
// 128x128 block tile, 256 threads = 4 waves 2x2, each wave 64x64 via 4x4
// v_mfma_f32_16x16x32_bf16. global_load_lds width-16 staging (m97 pattern).
// BK=32: unpadded [128][32], verified layout. BK=64: [128][64] with XOR
// swizzle col8 ^= (row&7) applied to the STAGING SOURCE address (LDS dest of
// global_load_lds must stay lane-contiguous) and to frag-read addresses, so
// ds_read_b128 stays 2-lanes/bank (free).
// Split-K: gridDim.z = splits*nbat, z = s*nbat + b; partial slot s at
// C + z*strideC (layout [s][b][M][N]).
// Verified layouts (cdna_hip_programming.md §3):
//   A frag: lane holds A[m = lane&15][k = (lane>>4)*8 + j], j=0..7
//   C/D   : col = lane&15, row = (lane>>4)*4 + reg
// ---------------------------------------------------------------------------
template <typename OutT, int BK>
__global__ __launch_bounds__(256) void gemm_bt(
    const bf16* __restrict__ A, const bf16* __restrict__ B, OutT* __restrict__ C,
    int M, int N, int K, long strideA, long strideB, long strideC,
    float scale, int nbat, int splits)
{
    const int z = blockIdx.z;
    const int b = z % nbat;
    const int s = z / nbat;
    const int klen = K / splits;
    const int k0 = s * klen;

    A += (long)b * strideA;
    B += (long)b * strideB;
    C += (long)z * strideC;

    const int bm = blockIdx.y * 128;
    const int bn = blockIdx.x * 128;
    const int tid = threadIdx.x;
    const int lane = tid & 63;
    const int wave = tid >> 6;
    const int wm = (wave >> 1) * 64;
    const int wn = (wave & 1) * 64;

    __shared__ bf16 As[128][BK];
    __shared__ bf16 Bs[128][BK];

    floatx4 acc[4][4];
#pragma unroll
    for (int i = 0; i < 4; i++)
#pragma unroll
        for (int j = 0; j < 4; j++) acc[i][j] = (floatx4)(0.0f);

    constexpr int LPR = BK / 8;    // lanes per LDS row
    constexpr int RPI = 512 / BK;  // rows covered per async instr
    const int srow = lane / LPR;
    int scol;
    if constexpr (BK == 64) scol = ((lane & 7) ^ (srow & 7)) * 8;
    else                    scol = (lane & 3) * 8;

    const int mrow = lane & 15;

    for (int kb = k0; kb < k0 + klen; kb += BK) {
        const bf16* Ag = A + (long)(bm + wave * 32 + srow) * K + kb + scol;
        const bf16* Bg = B + (long)(bn + wave * 32 + srow) * K + kb + scol;
#pragma unroll
        for (int u = 0; u < BK / 16; u++) {
            async_copy16(Ag + (long)(u * RPI) * K, &As[wave * 32 + u * RPI][0]);
            async_copy16(Bg + (long)(u * RPI) * K, &Bs[wave * 32 + u * RPI][0]);
        }
        __syncthreads();

#pragma unroll
        for (int kk = 0; kk < BK; kk += 32) {
            const int kc8 = (lane >> 4) + (kk >> 3);
            short8 af[4], bf[4];
#pragma unroll
            for (int i = 0; i < 4; i++) {
                int col8 = (BK == 64) ? (kc8 ^ (mrow & 7)) : kc8;
                af[i] = *(const short8*)(&As[wm + i * 16 + mrow][col8 * 8]);
            }
#pragma unroll
            for (int j = 0; j < 4; j++) {
                int col8 = (BK == 64) ? (kc8 ^ (mrow & 7)) : kc8;
                bf[j] = *(const short8*)(&Bs[wn + j * 16 + mrow][col8 * 8]);
            }
#pragma unroll
            for (int i = 0; i < 4; i++)
#pragma unroll
                for (int j = 0; j < 4; j++)
                    acc[i][j] = __builtin_amdgcn_mfma_f32_16x16x32_bf16(
                        af[i], bf[j], acc[i][j], 0, 0, 0);
        }
        __syncthreads();
    }

    const int crow = (lane >> 4) * 4;
    const int ccol = lane & 15;
#pragma unroll
    for (int i = 0; i < 4; i++) {
#pragma unroll
        for (int j = 0; j < 4; j++) {
#pragma unroll
            for (int r = 0; r < 4; r++) {
                long rr = bm + wm + i * 16 + crow + r;
                long cc = bn + wn + j * 16 + ccol;
                float v = acc[i][j][r] * scale;
                if constexpr (__is_same(OutT, float))
                    C[rr * (long)N + cc] = v;
                else
                    C[rr * (long)N + cc] = __float2bfloat16(v);
            }
        }
    }
}

// ---------------------------------------------------------------------------
// Column stats of S1 [B][NP][NC]: per (b,c) partial sum/sq/max over a 256-row
// slab. part: [B][16][NC] float4.
// ---------------------------------------------------------------------------
__global__ __launch_bounds__(256) void colstats_partial(
    const float* __restrict__ S, float4* __restrict__ part)
{
    const int b = blockIdx.z, c0 = blockIdx.x * 64, slab = blockIdx.y;
    const int tid = threadIdx.x;
    const int c = tid & 63, r = tid >> 6;
    const float* s = S + ((long)b * NPc + slab * 256) * NCc + c0 + c;
    float sum = 0.f, sq = 0.f, mx = -3.4e38f;
#pragma unroll 8
    for (int k = 0; k < 64; k++) {
        float x = s[(long)(k * 4 + r) * NCc];
        sum += x; sq += x * x; mx = fmaxf(mx, x);
    }
    __shared__ float red[3][4][64];
    red[0][r][c] = sum; red[1][r][c] = sq; red[2][r][c] = mx;
    __syncthreads();
    if (tid < 64) {
        float s0 = 0.f, q0 = 0.f, m0 = -3.4e38f;
#pragma unroll
        for (int i = 0; i < 4; i++) {
            s0 += red[0][i][tid]; q0 += red[1][i][tid];
            m0 = fmaxf(m0, red[2][i][tid]);
        }
        part[((long)b * 16 + slab) * NCc + c0 + tid] = make_float4(s0, q0, m0, 0.f);
    }
}

// Finalize: thr = mean + std(ddof=1)/8, keep max; zero denom. grid 16x256.
__global__ __launch_bounds__(256) void colstats_final(
    const float4* __restrict__ part, float2* __restrict__ thrmax,
    float* __restrict__ denom)
{
    int idx = blockIdx.x * 256 + threadIdx.x;  // 0 .. B*NC-1
    int b = idx >> 10, c = idx & 1023;
    float s = 0.f, q = 0.f, m = -3.4e38f;
#pragma unroll
    for (int i = 0; i < 16; i++) {
        float4 p = part[((long)b * 16 + i) * NCc + c];
        s += p.x; q += p.y; m = fmaxf(m, p.z);
    }
    float mean = s * (1.0f / NPc);
    float var = fmaxf((q - (float)NPc * mean * mean) * (1.0f / (NPc - 1)), 0.0f);
    thrmax[idx] = make_float2(mean + sqrtf(var) * 0.125f, m);
    denom[idx] = 0.f;
}

// ---------------------------------------------------------------------------
// Fused masked-exp + transpose: P[c][p] = (S[p][c] >= thr_c) ? exp(S-max_c) : 0
// (UNNORMALIZED; denom accumulated via atomics, folded into split-K reduce).
// Block: 64 cols x 256 rows. Transposed write staged through LDS.
// ---------------------------------------------------------------------------
__global__ __launch_bounds__(256) void softmax_T(
    const float* __restrict__ S, const float2* __restrict__ thrmax,
    float* __restrict__ denom, bf16* __restrict__ P)
{
    const int b = blockIdx.z, c0 = blockIdx.x * 64, p0 = blockIdx.y * 256;
    const int tid = threadIdx.x;
    const int c = tid & 63, r = tid >> 6;
    __shared__ float T[64][65];
    __shared__ float dred[4][64];
    const float2 tm = thrmax[b * NCc + c0 + c];
    const float* s = S + ((long)b * NPc + p0) * NCc + c0 + c;
    float dacc = 0.f;
    const int c2 = tid >> 2, j = tid & 3;
#pragma unroll
    for (int sub = 0; sub < 4; sub++) {
#pragma unroll
        for (int k = 0; k < 16; k++) {
            const int lr = k * 4 + r;
            float x = s[(long)(sub * 64 + lr) * NCc];
            float e = (x >= tm.x) ? __expf(x - tm.y) : 0.0f;
            dacc += e;
            T[c][lr] = e;
        }
        __syncthreads();
        bf16 tmp[16];
#pragma unroll
        for (int t = 0; t < 16; t++)
            tmp[t] = __float2bfloat16(T[c2][j * 16 + t]);
        bf16* dst = P + ((long)(b * NCc + c0 + c2)) * NPc + p0 + sub * 64 + j * 16;
        *(short8*)(dst)     = *(const short8*)(&tmp[0]);
        *(short8*)(dst + 8) = *(const short8*)(&tmp[8]);
        __syncthreads();
    }
    dred[r][c] = dacc;
    __syncthreads();
    if (tid < 64) {
        float d = dred[0][tid] + dred[1][tid] + dred[2][tid] + dred[3][tid];
        atomicAdd(&denom[b * NCc + c0 + tid], d);
    }
}

// ---------------------------------------------------------------------------
// Sum SPL split-K fp32 partials, scale row (b*NC+c) by 1/denom -> bf16
// ---------------------------------------------------------------------------
template <int SPL>
__global__ __launch_bounds__(256) void reduce_scale_bf16(
    const float* __restrict__ Pp, const float* __restrict__ denom,
    bf16* __restrict__ out, long n4, long stride)
{
    long i = (long)blockIdx.x * 256 + threadIdx.x;
    if (i < n4) {
        float4 a = ((const float4*)Pp)[i];
#pragma unroll
        for (int s = 1; s < SPL; s++) {
            float4 b = ((const float4*)(Pp + (long)s * stride))[i];
            a.x += b.x; a.y += b.y; a.z += b.z; a.w += b.w;
        }
        float inv = 1.0f / denom[i / (Dc / 4)];
        out[i * 4 + 0] = __float2bfloat16(a.x * inv);
        out[i * 4 + 1] = __float2bfloat16(a.y * inv);
        out[i * 4 + 2] = __float2bfloat16(a.z * inv);
        out[i * 4 + 3] = __float2bfloat16(a.w * inv);
    }
}

// ---------------------------------------------------------------------------
// Row-wise masked softmax (p2c path): thr = mean + std(ddof=1)/8.
// ---------------------------------------------------------------------------
__device__ inline float wred_sum(float x) {
#pragma unroll
    for (int o = 32; o; o >>= 1) x += __shfl_xor(x, o);
    return x;
}
__device__ inline float wred_max(float x) {
#pragma unroll
    for (int o = 32; o; o >>= 1) x = fmaxf(x, __shfl_xor(x, o));
    return x;
}

template <int NK>
__global__ __launch_bounds__(256) void masked_softmax_k(
    const float* __restrict__ S, bf16* __restrict__ P)
{
    constexpr int EPT = NK / 256;
    const long row = blockIdx.x;
    const float* s = S + row * (long)NK;
    bf16* p = P + row * (long)NK;
    const int tid = threadIdx.x;
    const int lane = tid & 63, wave = tid >> 6;

    float v[EPT];
    float sum = 0.f, sq = 0.f, mx = -1e30f;
#pragma unroll
    for (int i = 0; i < EPT; i++) {
        float x = s[tid + i * 256];
        v[i] = x;
        sum += x;
        sq += x * x;
        mx = fmaxf(mx, x);
    }

    __shared__ float red[3][4];
    float a = wred_sum(sum), b2 = wred_sum(sq), c = wred_max(mx);
    if (lane == 0) { red[0][wave] = a; red[1][wave] = b2; red[2][wave] = c; }
    __syncthreads();
    sum = red[0][0] + red[0][1] + red[0][2] + red[0][3];
    sq  = red[1][0] + red[1][1] + red[1][2] + red[1][3];
    mx  = fmaxf(fmaxf(red[2][0], red[2][1]), fmaxf(red[2][2], red[2][3]));

    float mean = sum * (1.0f / NK);
    float var = fmaxf((sq - (float)NK * mean * mean) * (1.0f / (NK - 1)), 0.0f);
    float thr = mean + sqrtf(var) * 0.125f;

    float e[EPT];
    float es = 0.f;
#pragma unroll
    for (int i = 0; i < EPT; i++) {
        float x = (v[i] >= thr) ? __expf(v[i] - mx) : 0.0f;
        e[i] = x;
        es += x;
    }
    __syncthreads();
    float w = wred_sum(es);
    if (lane == 0) red[0][wave] = w;
    __syncthreads();
    es = red[0][0] + red[0][1] + red[0][2] + red[0][3];
    float inv = 1.0f / es;
#pragma unroll
    for (int i = 0; i < EPT; i++)
        p[tid + i * 256] = __float2bfloat16(e[i] * inv);
}

// ---------------------------------------------------------------------------
__global__ __launch_bounds__(256) void cvt_f32_bf16(
    const float* __restrict__ in, bf16* __restrict__ out, long n4)
{
    long i = (long)blockIdx.x * 256 + threadIdx.x;
    if (i < n4) {
        float4 f = ((const float4*)in)[i];
        out[i * 4 + 0] = __float2bfloat16(f.x);
        out[i * 4 + 1] = __float2bfloat16(f.y);
        out[i * 4 + 2] = __float2bfloat16(f.z);
        out[i * 4 + 3] = __float2bfloat16(f.w);
    }
}

__global__ __launch_bounds__(256) void transpose_f32_bf16(
    const float* __restrict__ in, bf16* __restrict__ out, int R, int C)
{
    __shared__ float tile[32][33];
    const long boff = (long)blockIdx.z * (long)R * C;
    in += boff;
    out += boff;
    const int c0 = blockIdx.x * 32, r0 = blockIdx.y * 32;
    const int tx = threadIdx.x, ty = threadIdx.y;
#pragma unroll
    for (int i = ty; i < 32; i += 8)
        tile[i][tx] = in[(long)(r0 + i) * C + c0 + tx];
    __syncthreads();
#pragma unroll
    for (int i = ty; i < 32; i += 8)
        out[(long)(c0 + i) * R + r0 + tx] = __float2bfloat16(tile[tx][i]);
}

// ---------------------------------------------------------------------------
extern "C" void kernel_launch(void* const* d_in, const int* in_sizes, int n_in,
                              void* d_out, int out_size, void* d_ws, size_t ws_size,
                              hipStream_t stream)
{
    const float* Xp = (const float*)d_in[0];  // [4,4096,512]
    const float* Xc = (const float*)d_in[1];  // [4,1024,512]
    float* out = (float*)d_out;               // [4,4096,1024]

    constexpr int B = Bc, NP = NPc, NC = NCc, D = Dc;
    constexpr float SCALE = 0.044194173824159216f;  // 1/sqrt(512)

    // workspace layout (bytes) — total ~164.7 MB
    char* ws = (char*)d_ws;
    bf16*   Qp    = (bf16*)(ws);                    // 16.78 MB [B,NP,D]
    bf16*   Kc    = (bf16*)(ws + 16777216);         //  4.19 MB [B,NC,D]
    bf16*   KcT   = (bf16*)(ws + 20971520);         //  4.19 MB [B,D,NC]
    bf16*   XpT   = (bf16*)(ws + 25165824);         // 16.78 MB [B,D,NP]
    float*  S     = (float*)(ws + 41943040);        // 67.1 MB [B,NP,NC] S1; later 8-way split-K partials
    bf16*   Aw    = (bf16*)(ws + 109051904);        // 33.55 MB A1, then unnormalized A2
    bf16*   H1    = (bf16*)(ws + 142606336);        // 16.78 MB [B,NP,D]
    bf16*   H2    = (bf16*)(ws + 159383552);        //  4.19 MB [B,NC,D]
    float4* cstat = (float4*)(ws + 163577856);      //  1.05 MB [B,16,NC]
    float2* thrmx = (float2*)(ws + 164626432);      //  32 KB  [B*NC]
    float*  denom = (float*)(ws + 164659200);       //  16 KB  [B*NC]
    float*  Hp    = S;                              // split-K partials [8][B,NC,D] fp32 = 67.1 MB

    // 1-2: convert inputs to bf16
    {
        long n4 = (long)B * NP * D / 4;
        cvt_f32_bf16<<<dim3((n4 + 255) / 256), dim3(256), 0, stream>>>(Xp, Qp, n4);
        n4 = (long)B * NC * D / 4;
        cvt_f32_bf16<<<dim3((n4 + 255) / 256), dim3(256), 0, stream>>>(Xc, Kc, n4);
    }
    // 3-4: transposed bf16 copies
    transpose_f32_bf16<<<dim3(D / 32, NC / 32, B), dim3(32, 8), 0, stream>>>(Xc, KcT, NC, D);
    transpose_f32_bf16<<<dim3(D / 32, NP / 32, B), dim3(32, 8), 0, stream>>>(Xp, XpT, NP, D);

    // 5: S1 = Qp * Kc^T * scale      [B, NP, NC] fp32   (BK=64 A/B test arm)
    gemm_bt<float, 64><<<dim3(NC / 128, NP / 128, B), dim3(256), 0, stream>>>(
        Qp, Kc, S, NP, NC, D, (long)NP * D, (long)NC * D, (long)NP * NC, SCALE, B, 1);
    // 6: A1 = row masked_softmax(S1) [B, NP, NC] bf16
    masked_softmax_k<NC><<<dim3(B * NP), dim3(256), 0, stream>>>(S, Aw);
    // 7: H1 = A1 * Kc                [B, NP, D] bf16
    gemm_bt<bf16, 32><<<dim3(D / 128, NP / 128, B), dim3(256), 0, stream>>>(
        Aw, KcT, H1, NP, D, NC, (long)NP * NC, (long)D * NC, (long)NP * D, 1.0f, B, 1);
    // 8: c2p path from S1^T (S2 == S1^T): column stats -> thr/max; zero denom
    colstats_partial<<<dim3(NC / 64, NP / 256, B), dim3(256), 0, stream>>>(S, cstat);
    colstats_final<<<dim3(B * NC / 256), dim3(256), 0, stream>>>(cstat, thrmx, denom);
    // 9: A2u = masked exp(S1^T) unnormalized [B, NC, NP] bf16; denom via atomics
    softmax_T<<<dim3(NC / 64, NP / 256, B), dim3(256), 0, stream>>>(S, thrmx, denom, Aw);
    // 10: H2 = (A2u * Xp) / denom    [B, NC, D] bf16, 8-way split-K
    gemm_bt<float, 32><<<dim3(D / 128, NC / 128, 8 * B), dim3(256), 0, stream>>>(
        Aw, XpT, Hp, NC, D, NP, (long)NC * NP, (long)D * NP, (long)NC * D, 1.0f, B, 8);
    {
        long n = (long)B * NC * D;
        reduce_scale_bf16<8><<<dim3((n / 4 + 255) / 256), dim3(256), 0, stream>>>(
            Hp, denom, H2, n / 4, n);
    }
    // 11: out = H1 * H2^T            [B, NP, NC] fp32   (BK=32 A/B control arm)
    gemm_bt<float, 32><<<dim3(NC / 128, NP / 128, B), dim3(256), 0, stream>>>(
        H1, H2, out, NP, NC, D, (long)NP * D, (long)NC * D, (long)NP * NC, 1.0f, B, 1);
}

// Round 4
// 312.542 us; speedup vs baseline: 1.0875x; 1.0875x over previous
//
#include <hip/hip_runtime.h>
#include <hip/hip_bf16.h>

using bf16 = __hip_bfloat16;
typedef __attribute__((ext_vector_type(8))) short short8;   // 8 bf16 (4 VGPRs)
typedef __attribute__((ext_vector_type(4))) float floatx4;  // MFMA C/D frag

#define NPn 4096
#define NCn 1024
#define Dn  512
#define Bn  4

__device__ __forceinline__ float b2f(short s) {
    union { unsigned u; float f; } cv;
    cv.u = ((unsigned)(unsigned short)s) << 16;
    return cv.f;
}

// ---------------------------------------------------------------------------
// async global->LDS, 16B per lane. LDS dest = (wave-uniform base) + lane*16B.
// ---------------------------------------------------------------------------
__device__ __forceinline__ void async_copy16(const bf16* g, bf16* l) {
    __builtin_amdgcn_global_load_lds(
        (const __attribute__((address_space(1))) unsigned int*)g,
        (__attribute__((address_space(3))) unsigned int*)l,
        16, 0, 0);
}

// ---------------------------------------------------------------------------
// C[M x N] = scale * A[M x K] * Bt[N x K]^T  (both row-major bf16)
// 128x128 tile, BK=32, 4 waves 2x2, 4x4 mfma_f32_16x16x32_bf16 per wave.
// m97-pattern global_load_lds staging, unpadded [128][32] LDS.
// RS: multiply output row rr by 1/rsc[b*M+rr] (folded softmax normalization).
// Split-K: z = s*nbat + b; partial slot s at C + z*strideC.
// ---------------------------------------------------------------------------
template <typename OutT, bool RS>
__global__ __launch_bounds__(256) void gemm_bt(
    const bf16* __restrict__ A, const bf16* __restrict__ B, OutT* __restrict__ C,
    int M, int N, int K, long strideA, long strideB, long strideC,
    float scale, int nbat, int splits, const float* __restrict__ rsc)
{
    const int z = blockIdx.z;
    const int b = z % nbat;
    const int s = z / nbat;
    const int klen = K / splits;
    const int k0 = s * klen;

    A += (long)b * strideA;
    B += (long)b * strideB;
    C += (long)z * strideC;

    const int bm = blockIdx.y * 128;
    const int bn = blockIdx.x * 128;
    const int tid = threadIdx.x;
    const int lane = tid & 63;
    const int wave = tid >> 6;
    const int wm = (wave >> 1) * 64;
    const int wn = (wave & 1) * 64;

    __shared__ bf16 As[128][32];
    __shared__ bf16 Bs[128][32];

    floatx4 acc[4][4];
#pragma unroll
    for (int i = 0; i < 4; i++)
#pragma unroll
        for (int j = 0; j < 4; j++) acc[i][j] = (floatx4)(0.0f);

    const int srow = lane >> 2;
    const int scol = (lane & 3) * 8;
    const int mrow = lane & 15;
    const int krow = (lane >> 4) * 8;

    for (int kb = k0; kb < k0 + klen; kb += 32) {
        const bf16* Ag = A + (long)(bm + wave * 32 + srow) * K + kb + scol;
        const bf16* Bg = B + (long)(bn + wave * 32 + srow) * K + kb + scol;
        async_copy16(Ag,           &As[wave * 32][0]);
        async_copy16(Ag + 16L * K, &As[wave * 32 + 16][0]);
        async_copy16(Bg,           &Bs[wave * 32][0]);
        async_copy16(Bg + 16L * K, &Bs[wave * 32 + 16][0]);
        __syncthreads();

        short8 af[4], bf[4];
#pragma unroll
        for (int i = 0; i < 4; i++)
            af[i] = *(const short8*)(&As[wm + i * 16 + mrow][krow]);
#pragma unroll
        for (int j = 0; j < 4; j++)
            bf[j] = *(const short8*)(&Bs[wn + j * 16 + mrow][krow]);

#pragma unroll
        for (int i = 0; i < 4; i++)
#pragma unroll
            for (int j = 0; j < 4; j++)
                acc[i][j] = __builtin_amdgcn_mfma_f32_16x16x32_bf16(
                    af[i], bf[j], acc[i][j], 0, 0, 0);
        __syncthreads();
    }

    const int crow = (lane >> 4) * 4;
    const int ccol = lane & 15;
    float inv_[4][4];
#pragma unroll
    for (int i = 0; i < 4; i++)
#pragma unroll
        for (int r = 0; r < 4; r++) {
            if constexpr (RS)
                inv_[i][r] = 1.0f / rsc[(long)b * M + bm + wm + i * 16 + crow + r];
            else
                inv_[i][r] = 1.0f;
        }
#pragma unroll
    for (int i = 0; i < 4; i++) {
#pragma unroll
        for (int j = 0; j < 4; j++) {
#pragma unroll
            for (int r = 0; r < 4; r++) {
                long rr = bm + wm + i * 16 + crow + r;
                long cc = bn + wn + j * 16 + ccol;
                float v = acc[i][j][r] * scale * inv_[i][r];
                if constexpr (__is_same(OutT, float))
                    C[rr * (long)N + cc] = v;
                else
                    C[rr * (long)N + cc] = __float2bfloat16(v);
            }
        }
    }
}

// ---------------------------------------------------------------------------
// S1 GEMM with fused row/col stat partials.  Fixed shape M=NP,N=NC,K=D.
// Writes S bf16 and per-block partials:
//   rp[(b*8+bx)*NP + row]  = (sum,sq,max) over this block's 128 cols
//   cp[(b*32+by)*NC + col] = (sum,sq,max) over this block's 128 rows
// ---------------------------------------------------------------------------
__global__ __launch_bounds__(256) void gemm_stats(
    const bf16* __restrict__ A, const bf16* __restrict__ B, bf16* __restrict__ S,
    float4* __restrict__ rp, float4* __restrict__ cp, float scale)
{
    const int b = blockIdx.z;
    const int M = NPn, N = NCn, K = Dn;
    A += (long)b * NPn * Dn;
    B += (long)b * NCn * Dn;
    S += (long)b * NPn * NCn;

    const int bm = blockIdx.y * 128;
    const int bn = blockIdx.x * 128;
    const int tid = threadIdx.x;
    const int lane = tid & 63;
    const int wave = tid >> 6;
    const int wm = (wave >> 1) * 64;
    const int wn = (wave & 1) * 64;

    __shared__ bf16 As[128][32];
    __shared__ bf16 Bs[128][32];
    __shared__ float4 LR[2][128];
    __shared__ float4 LC[2][128];

    floatx4 acc[4][4];
#pragma unroll
    for (int i = 0; i < 4; i++)
#pragma unroll
        for (int j = 0; j < 4; j++) acc[i][j] = (floatx4)(0.0f);

    const int srow = lane >> 2;
    const int scol = (lane & 3) * 8;
    const int mrow = lane & 15;
    const int krow = (lane >> 4) * 8;

    for (int kb = 0; kb < K; kb += 32) {
        const bf16* Ag = A + (long)(bm + wave * 32 + srow) * K + kb + scol;
        const bf16* Bg = B + (long)(bn + wave * 32 + srow) * K + kb + scol;
        async_copy16(Ag,           &As[wave * 32][0]);
        async_copy16(Ag + 16L * K, &As[wave * 32 + 16][0]);
        async_copy16(Bg,           &Bs[wave * 32][0]);
        async_copy16(Bg + 16L * K, &Bs[wave * 32 + 16][0]);
        __syncthreads();

        short8 af[4], bf[4];
#pragma unroll
        for (int i = 0; i < 4; i++)
            af[i] = *(const short8*)(&As[wm + i * 16 + mrow][krow]);
#pragma unroll
        for (int j = 0; j < 4; j++)
            bf[j] = *(const short8*)(&Bs[wn + j * 16 + mrow][krow]);

#pragma unroll
        for (int i = 0; i < 4; i++)
#pragma unroll
            for (int j = 0; j < 4; j++)
                acc[i][j] = __builtin_amdgcn_mfma_f32_16x16x32_bf16(
                    af[i], bf[j], acc[i][j], 0, 0, 0);
        __syncthreads();
    }

    const int crow = (lane >> 4) * 4;
    const int ccol = lane & 15;

    float rs_[4][4], rq_[4][4], rm_[4][4];    // [i][r] over this wave's 64 cols? (j,ccol)
    float cs_[4], cq_[4], cm_[4];             // [j]
#pragma unroll
    for (int i = 0; i < 4; i++)
#pragma unroll
        for (int r = 0; r < 4; r++) { rs_[i][r] = 0.f; rq_[i][r] = 0.f; rm_[i][r] = -3.4e38f; }
#pragma unroll
    for (int j = 0; j < 4; j++) { cs_[j] = 0.f; cq_[j] = 0.f; cm_[j] = -3.4e38f; }

#pragma unroll
    for (int i = 0; i < 4; i++) {
#pragma unroll
        for (int j = 0; j < 4; j++) {
#pragma unroll
            for (int r = 0; r < 4; r++) {
                long rr = bm + wm + i * 16 + crow + r;
                long cc = bn + wn + j * 16 + ccol;
                float v = acc[i][j][r] * scale;
                S[rr * (long)N + cc] = __float2bfloat16(v);
                rs_[i][r] += v; rq_[i][r] += v * v; rm_[i][r] = fmaxf(rm_[i][r], v);
                cs_[j] += v;    cq_[j] += v * v;    cm_[j] = fmaxf(cm_[j], v);
            }
        }
    }
    // row reduce across the 16 lanes of a quad (different ccol)
#pragma unroll
    for (int m = 1; m < 16; m <<= 1) {
#pragma unroll
        for (int i = 0; i < 4; i++)
#pragma unroll
            for (int r = 0; r < 4; r++) {
                rs_[i][r] += __shfl_xor(rs_[i][r], m);
                rq_[i][r] += __shfl_xor(rq_[i][r], m);
                rm_[i][r] = fmaxf(rm_[i][r], __shfl_xor(rm_[i][r], m));
            }
    }
    if ((lane & 15) == 0) {
        const int q = lane >> 4;
#pragma unroll
        for (int i = 0; i < 4; i++)
#pragma unroll
            for (int r = 0; r < 4; r++)
                LR[wave & 1][wm + i * 16 + q * 4 + r] =
                    make_float4(rs_[i][r], rq_[i][r], rm_[i][r], 0.f);
    }
    // col reduce across quads
#pragma unroll
    for (int m = 16; m < 64; m <<= 1) {
#pragma unroll
        for (int j = 0; j < 4; j++) {
            cs_[j] += __shfl_xor(cs_[j], m);
            cq_[j] += __shfl_xor(cq_[j], m);
            cm_[j] = fmaxf(cm_[j], __shfl_xor(cm_[j], m));
        }
    }
    if (lane < 16) {
#pragma unroll
        for (int j = 0; j < 4; j++)
            LC[wave >> 1][wn + j * 16 + lane] = make_float4(cs_[j], cq_[j], cm_[j], 0.f);
    }
    __syncthreads();
    if (tid < 128) {
        float4 a = LR[0][tid], c = LR[1][tid];
        rp[((long)(b * 8 + blockIdx.x)) * NPn + bm + tid] =
            make_float4(a.x + c.x, a.y + c.y, fmaxf(a.z, c.z), 0.f);
    } else {
        int t = tid - 128;
        float4 a = LC[0][t], c = LC[1][t];
        cp[((long)(b * 32 + blockIdx.y)) * NCn + bn + t] =
            make_float4(a.x + c.x, a.y + c.y, fmaxf(a.z, c.z), 0.f);
    }
}

// ---------------------------------------------------------------------------
// Finalize stats: rows (B*NP entries, reduce 8 partials, N=NC) then cols
// (B*NC entries, reduce 32 partials, N=NP). thr = mean + std(ddof=1)/8.
// Also zeros d1/d2 (denominator accumulators).
// ---------------------------------------------------------------------------
__global__ __launch_bounds__(256) void stats_final(
    const float4* __restrict__ rp, const float4* __restrict__ cp,
    float2* __restrict__ row_tm, float2* __restrict__ col_tm,
    float* __restrict__ d1, float* __restrict__ d2)
{
    int idx = blockIdx.x * 256 + threadIdx.x;   // 0 .. B*NP + B*NC - 1
    if (idx < Bn * NPn) {
        int b = idx >> 12, p = idx & (NPn - 1);
        float s = 0.f, q = 0.f, m = -3.4e38f;
#pragma unroll
        for (int i = 0; i < 8; i++) {
            float4 v = rp[((long)(b * 8 + i)) * NPn + p];
            s += v.x; q += v.y; m = fmaxf(m, v.z);
        }
        float mean = s * (1.0f / NCn);
        float var = fmaxf((q - (float)NCn * mean * mean) * (1.0f / (NCn - 1)), 0.0f);
        row_tm[idx] = make_float2(mean + sqrtf(var) * 0.125f, m);
        d1[idx] = 0.f;
    } else {
        int cidx = idx - Bn * NPn;
        int b = cidx >> 10, c = cidx & (NCn - 1);
        float s = 0.f, q = 0.f, m = -3.4e38f;
#pragma unroll
        for (int i = 0; i < 32; i++) {
            float4 v = cp[((long)(b * 32 + i)) * NCn + c];
            s += v.x; q += v.y; m = fmaxf(m, v.z);
        }
        float mean = s * (1.0f / NPn);
        float var = fmaxf((q - (float)NPn * mean * mean) * (1.0f / (NPn - 1)), 0.0f);
        col_tm[cidx] = make_float2(mean + sqrtf(var) * 0.125f, m);
        d2[cidx] = 0.f;
    }
}

// ---------------------------------------------------------------------------
// Merged masked softmax: one read of S (bf16) produces
//   A1u[p][c] = (s>=thr_r[p]) ? exp(s-mx_r[p]) : 0    (row-major, unnormalized)
//   A2u[c][p] = (s>=thr_c[c]) ? exp(s-mx_c[c]) : 0    (transposed via LDS)
// d1[p], d2[c] accumulated via device atomics; normalization folded downstream.
// Tile: 256 rows x 64 cols. 256 threads.
// ---------------------------------------------------------------------------
__global__ __launch_bounds__(256) void softmax_merged(
    const bf16* __restrict__ S, const float2* __restrict__ row_tm,
    const float2* __restrict__ col_tm, float* __restrict__ d1,
    float* __restrict__ d2, bf16* __restrict__ A1u, bf16* __restrict__ A2u)
{
    const int b = blockIdx.z, c0 = blockIdx.x * 64, p0 = blockIdx.y * 256;
    const int tid = threadIdx.x;
    const int rt = tid >> 3;          // 0..31 row within pass
    const int ct = (tid & 7) * 8;     // col offset, 8 cols per thread

    __shared__ float T[64][265];      // transposed e2 staging (stride 265: 2-way-free writes)
    __shared__ float dw2[4][64];      // per-wave col-denom partials

    float2 ctm[8];
#pragma unroll
    for (int t = 0; t < 8; t++) ctm[t] = col_tm[b * NCn + c0 + ct + t];

    float d2acc[8];
#pragma unroll
    for (int t = 0; t < 8; t++) d2acc[t] = 0.f;

#pragma unroll
    for (int pass = 0; pass < 8; pass++) {
        const int p = p0 + pass * 32 + rt;
        const float2 rtm = row_tm[b * NPn + p];
        const long sidx = ((long)(b * NPn + p)) * NCn + c0 + ct;
        short8 sv = *(const short8*)(S + sidx);
        bf16 o1[8] __attribute__((aligned(16)));
        float e1s = 0.f;
#pragma unroll
        for (int t = 0; t < 8; t++) {
            float x = b2f(sv[t]);
            float e1 = (x >= rtm.x) ? __expf(x - rtm.y) : 0.0f;
            o1[t] = __float2bfloat16(e1);
            e1s += e1;
            float e2 = (x >= ctm[t].x) ? __expf(x - ctm[t].y) : 0.0f;
            d2acc[t] += e2;
            T[ct + t][pass * 32 + rt] = e2;
        }
        *(short8*)(A1u + sidx) = *(const short8*)o1;
        e1s += __shfl_xor(e1s, 1);
        e1s += __shfl_xor(e1s, 2);
        e1s += __shfl_xor(e1s, 4);
        if ((tid & 7) == 0) atomicAdd(&d1[b * NPn + p], e1s);
    }

    // col denominators: reduce d2acc across rt within wave (xor 8,16,32), then LDS
#pragma unroll
    for (int m = 8; m < 64; m <<= 1)
#pragma unroll
        for (int t = 0; t < 8; t++) d2acc[t] += __shfl_xor(d2acc[t], m);
    const int lane = tid & 63, wave = tid >> 6;
    if (lane < 8)
#pragma unroll
        for (int t = 0; t < 8; t++) dw2[wave][lane * 8 + t] = d2acc[t];
    __syncthreads();
    if (tid < 64)
        atomicAdd(&d2[b * NCn + c0 + tid],
                  dw2[0][tid] + dw2[1][tid] + dw2[2][tid] + dw2[3][tid]);

    // write A2u (transposed tile) from LDS
    const int c = tid >> 2, pb = (tid & 3) * 64;
    bf16* dst = A2u + ((long)(b * NCn + c0 + c)) * NPn + p0 + pb;
#pragma unroll
    for (int u = 0; u < 8; u++) {
        bf16 tmp[8] __attribute__((aligned(16)));
#pragma unroll
        for (int w = 0; w < 8; w++)
            tmp[w] = __float2bfloat16(T[c][pb + u * 8 + w]);
        *(short8*)(dst + u * 8) = *(const short8*)tmp;
    }
}

// ---------------------------------------------------------------------------
// Sum 4 split-K fp32 partials, scale row (b*NC+c) by 1/d2 -> bf16
// ---------------------------------------------------------------------------
__global__ __launch_bounds__(256) void reduce_scale_bf16(
    const float* __restrict__ Pp, const float* __restrict__ d2,
    bf16* __restrict__ out, long n4, long stride)
{
    long i = (long)blockIdx.x * 256 + threadIdx.x;
    if (i < n4) {
        float4 a = ((const float4*)Pp)[i];
#pragma unroll
        for (int s = 1; s < 4; s++) {
            float4 v = ((const float4*)(Pp + (long)s * stride))[i];
            a.x += v.x; a.y += v.y; a.z += v.z; a.w += v.w;
        }
        float inv = 1.0f / d2[i / (Dn / 4)];
        out[i * 4 + 0] = __float2bfloat16(a.x * inv);
        out[i * 4 + 1] = __float2bfloat16(a.y * inv);
        out[i * 4 + 2] = __float2bfloat16(a.z * inv);
        out[i * 4 + 3] = __float2bfloat16(a.w * inv);
    }
}

// ---------------------------------------------------------------------------
// fp32 [R x C] -> bf16 row-major copy AND bf16 [C x R] transpose, batched z.
// ---------------------------------------------------------------------------
__global__ __launch_bounds__(256) void cvt_both(
    const float* __restrict__ in, bf16* __restrict__ out_rm,
    bf16* __restrict__ out_t, int R, int C)
{
    __shared__ float tile[32][33];
    const long boff = (long)blockIdx.z * (long)R * C;
    in += boff; out_rm += boff; out_t += boff;
    const int c0 = blockIdx.x * 32, r0 = blockIdx.y * 32;
    const int tx = threadIdx.x, ty = threadIdx.y;
#pragma unroll
    for (int i = ty; i < 32; i += 8) {
        float x = in[(long)(r0 + i) * C + c0 + tx];
        tile[i][tx] = x;
        out_rm[(long)(r0 + i) * C + c0 + tx] = __float2bfloat16(x);
    }
    __syncthreads();
#pragma unroll
    for (int i = ty; i < 32; i += 8)
        out_t[(long)(c0 + i) * R + r0 + tx] = __float2bfloat16(tile[tx][i]);
}

// ---------------------------------------------------------------------------
extern "C" void kernel_launch(void* const* d_in, const int* in_sizes, int n_in,
                              void* d_out, int out_size, void* d_ws, size_t ws_size,
                              hipStream_t stream)
{
    const float* Xp = (const float*)d_in[0];  // [4,4096,512]
    const float* Xc = (const float*)d_in[1];  // [4,1024,512]
    float* out = (float*)d_out;               // [4,4096,1024]

    constexpr int B = Bn, NP = NPn, NC = NCn, D = Dn;
    constexpr float SCALE = 0.044194173824159216f;  // 1/sqrt(512)

    // workspace layout (bytes), ~168 MB
    char* ws = (char*)d_ws;
    bf16*   Qp     = (bf16*)(ws);                   // 16.78 MB [B,NP,D]
    bf16*   Kc     = (bf16*)(ws + 16777216);        //  4.19 MB [B,NC,D]
    bf16*   KcT    = (bf16*)(ws + 20971520);        //  4.19 MB [B,D,NC]
    bf16*   XpT    = (bf16*)(ws + 25165824);        // 16.78 MB [B,D,NP]
    bf16*   S      = (bf16*)(ws + 41943040);        // 33.55 MB [B,NP,NC] bf16; later Hp overlays
    bf16*   A1u    = (bf16*)(ws + 75497472);        // 33.55 MB [B,NP,NC]
    bf16*   A2u    = (bf16*)(ws + 109051904);       // 33.55 MB [B,NC,NP]
    bf16*   H1u    = (bf16*)(ws + 142606336);       // 16.78 MB [B,NP,D]
    bf16*   H2     = (bf16*)(ws + 159383552);       //  4.19 MB [B,NC,D]
    float4* rp     = (float4*)(ws + 163577856);     //  2.10 MB [B*8,NP]
    float4* cp     = (float4*)(ws + 165675008);     //  2.10 MB [B*32,NC]
    float2* row_tm = (float2*)(ws + 167772160);     // 128 KB  [B*NP]
    float2* col_tm = (float2*)(ws + 167903232);     //  32 KB  [B*NC]
    float*  d1     = (float*)(ws + 167936000);      //  64 KB  [B*NP]
    float*  d2     = (float*)(ws + 168001536);      //  16 KB  [B*NC]
    float*  Hp     = (float*)S;                     // split-K partials [4][B,NC,D] fp32 (S dead)

    // 1-2: convert + transpose inputs (one read of fp32 each)
    cvt_both<<<dim3(D / 32, NP / 32, B), dim3(32, 8), 0, stream>>>(Xp, Qp, XpT, NP, D);
    cvt_both<<<dim3(D / 32, NC / 32, B), dim3(32, 8), 0, stream>>>(Xc, Kc, KcT, NC, D);

    // 3: S1 = Qp*Kc^T*scale (bf16) + fused row/col stat partials
    gemm_stats<<<dim3(NC / 128, NP / 128, B), dim3(256), 0, stream>>>(
        Qp, Kc, S, rp, cp, SCALE);
    // 4: finalize thr/max for rows and cols; zero denoms
    stats_final<<<dim3((B * NP + B * NC) / 256), dim3(256), 0, stream>>>(
        rp, cp, row_tm, col_tm, d1, d2);
    // 5: merged softmax -> A1u (row-major) + A2u (transposed), denoms via atomics
    softmax_merged<<<dim3(NC / 64, NP / 256, B), dim3(256), 0, stream>>>(
        S, row_tm, col_tm, d1, d2, A1u, A2u);
    // 6: H1u = A1u * Kc            [B,NP,D] bf16 (unnormalized; 1/d1 folded into step 9)
    gemm_bt<bf16, false><<<dim3(D / 128, NP / 128, B), dim3(256), 0, stream>>>(
        A1u, KcT, H1u, NP, D, NC, (long)NP * NC, (long)D * NC, (long)NP * D,
        1.0f, B, 1, nullptr);
    // 7: Hp = A2u * Xp partials    [4][B,NC,D] fp32, 4-way split-K
    gemm_bt<float, false><<<dim3(D / 128, NC / 128, 4 * B), dim3(256), 0, stream>>>(
        A2u, XpT, Hp, NC, D, NP, (long)NC * NP, (long)D * NP, (long)NC * D,
        1.0f, B, 4, nullptr);
    // 8: H2 = sum(Hp) / d2 -> bf16
    {
        long n = (long)B * NC * D;
        reduce_scale_bf16<<<dim3((n / 4 + 255) / 256), dim3(256), 0, stream>>>(
            Hp, d2, H2, n / 4, n);
    }
    // 9: out = diag(1/d1) * H1u * H2^T   [B,NP,NC] fp32
    gemm_bt<float, true><<<dim3(NC / 128, NP / 128, B), dim3(256), 0, stream>>>(
        H1u, H2, out, NP, NC, D, (long)NP * D, (long)NC * D, (long)NP * NC,
        1.0f, B, 1, d1);
}

// Round 5
// 300.531 us; speedup vs baseline: 1.1310x; 1.0400x over previous
//
#include <hip/hip_runtime.h>
#include <hip/hip_bf16.h>

using bf16 = __hip_bfloat16;
typedef __attribute__((ext_vector_type(8))) short short8;   // 8 bf16 (4 VGPRs)
typedef __attribute__((ext_vector_type(4))) float floatx4;  // MFMA C/D frag

#define NPn 4096
#define NCn 1024
#define Dn  512
#define Bn  4

__device__ __forceinline__ float b2f(short s) {
    union { unsigned u; float f; } cv;
    cv.u = ((unsigned)(unsigned short)s) << 16;
    return cv.f;
}

// ---------------------------------------------------------------------------
// async global->LDS, 16B per lane. LDS dest = (wave-uniform base) + lane*16B.
// ---------------------------------------------------------------------------
__device__ __forceinline__ void async_copy16(const bf16* g, bf16* l) {
    __builtin_amdgcn_global_load_lds(
        (const __attribute__((address_space(1))) unsigned int*)g,
        (__attribute__((address_space(3))) unsigned int*)l,
        16, 0, 0);
}

// ---------------------------------------------------------------------------
// C[M x N] = scale * A[M x K] * Bt[N x K]^T  (both row-major bf16)
// 128x128 tile, BK=32, 4 waves 2x2, 4x4 mfma_f32_16x16x32_bf16 per wave.
// m97-pattern global_load_lds staging, unpadded [128][32] LDS.
// RS: multiply output row rr by 1/rsc[b*M+rr] (folded softmax normalization).
// Split-K: z = s*nbat + b; partial slot s at C + z*strideC.
// ---------------------------------------------------------------------------
template <typename OutT, bool RS>
__global__ __launch_bounds__(256) void gemm_bt(
    const bf16* __restrict__ A, const bf16* __restrict__ B, OutT* __restrict__ C,
    int M, int N, int K, long strideA, long strideB, long strideC,
    float scale, int nbat, int splits, const float* __restrict__ rsc)
{
    const int z = blockIdx.z;
    const int b = z % nbat;
    const int s = z / nbat;
    const int klen = K / splits;
    const int k0 = s * klen;

    A += (long)b * strideA;
    B += (long)b * strideB;
    C += (long)z * strideC;

    const int bm = blockIdx.y * 128;
    const int bn = blockIdx.x * 128;
    const int tid = threadIdx.x;
    const int lane = tid & 63;
    const int wave = tid >> 6;
    const int wm = (wave >> 1) * 64;
    const int wn = (wave & 1) * 64;

    __shared__ bf16 As[128][32];
    __shared__ bf16 Bs[128][32];

    floatx4 acc[4][4];
#pragma unroll
    for (int i = 0; i < 4; i++)
#pragma unroll
        for (int j = 0; j < 4; j++) acc[i][j] = (floatx4)(0.0f);

    const int srow = lane >> 2;
    const int scol = (lane & 3) * 8;
    const int mrow = lane & 15;
    const int krow = (lane >> 4) * 8;

    for (int kb = k0; kb < k0 + klen; kb += 32) {
        const bf16* Ag = A + (long)(bm + wave * 32 + srow) * K + kb + scol;
        const bf16* Bg = B + (long)(bn + wave * 32 + srow) * K + kb + scol;
        async_copy16(Ag,           &As[wave * 32][0]);
        async_copy16(Ag + 16L * K, &As[wave * 32 + 16][0]);
        async_copy16(Bg,           &Bs[wave * 32][0]);
        async_copy16(Bg + 16L * K, &Bs[wave * 32 + 16][0]);
        __syncthreads();

        short8 af[4], bf[4];
#pragma unroll
        for (int i = 0; i < 4; i++)
            af[i] = *(const short8*)(&As[wm + i * 16 + mrow][krow]);
#pragma unroll
        for (int j = 0; j < 4; j++)
            bf[j] = *(const short8*)(&Bs[wn + j * 16 + mrow][krow]);

#pragma unroll
        for (int i = 0; i < 4; i++)
#pragma unroll
            for (int j = 0; j < 4; j++)
                acc[i][j] = __builtin_amdgcn_mfma_f32_16x16x32_bf16(
                    af[i], bf[j], acc[i][j], 0, 0, 0);
        __syncthreads();
    }

    const int crow = (lane >> 4) * 4;
    const int ccol = lane & 15;
    float inv_[4][4];
#pragma unroll
    for (int i = 0; i < 4; i++)
#pragma unroll
        for (int r = 0; r < 4; r++) {
            if constexpr (RS)
                inv_[i][r] = 1.0f / rsc[(long)b * M + bm + wm + i * 16 + crow + r];
            else
                inv_[i][r] = 1.0f;
        }
#pragma unroll
    for (int i = 0; i < 4; i++) {
#pragma unroll
        for (int j = 0; j < 4; j++) {
#pragma unroll
            for (int r = 0; r < 4; r++) {
                long rr = bm + wm + i * 16 + crow + r;
                long cc = bn + wn + j * 16 + ccol;
                float v = acc[i][j][r] * scale * inv_[i][r];
                if constexpr (__is_same(OutT, float))
                    C[rr * (long)N + cc] = v;
                else
                    C[rr * (long)N + cc] = __float2bfloat16(v);
            }
        }
    }
}

// ---------------------------------------------------------------------------
// One pass over S (bf16) producing BOTH row and col stat partials.
// Tile 256 rows x 64 cols, grid (NC/64, NP/256, B). Per-block unique slots:
//   rp[(b*16+bx)*NP + row] = (sum,sq,max) over this block's 64 cols
//   cp[(b*16+by)*NC + col] = (sum,sq,max) over this block's 256 rows
// ---------------------------------------------------------------------------
__global__ __launch_bounds__(256) void stats_both(
    const bf16* __restrict__ S, float4* __restrict__ rp, float4* __restrict__ cp)
{
    const int b = blockIdx.z, c0 = blockIdx.x * 64, p0 = blockIdx.y * 256;
    const int tid = threadIdx.x;
    const int rt = tid >> 3;          // 0..31 rows per pass
    const int ct = (tid & 7) * 8;     // 8 cols per thread

    float cs[8], cq[8], cm[8];
#pragma unroll
    for (int t = 0; t < 8; t++) { cs[t] = 0.f; cq[t] = 0.f; cm[t] = -3.4e38f; }

#pragma unroll
    for (int pass = 0; pass < 8; pass++) {
        const int p = p0 + pass * 32 + rt;
        const long sidx = ((long)(b * NPn + p)) * NCn + c0 + ct;
        short8 sv = *(const short8*)(S + sidx);
        float rs = 0.f, rq = 0.f, rm = -3.4e38f;
#pragma unroll
        for (int t = 0; t < 8; t++) {
            float x = b2f(sv[t]);
            rs += x; rq += x * x; rm = fmaxf(rm, x);
            cs[t] += x; cq[t] += x * x; cm[t] = fmaxf(cm[t], x);
        }
        // reduce over the 8 lanes covering this row
#pragma unroll
        for (int m = 1; m < 8; m <<= 1) {
            rs += __shfl_xor(rs, m);
            rq += __shfl_xor(rq, m);
            rm = fmaxf(rm, __shfl_xor(rm, m));
        }
        if ((tid & 7) == 0)
            rp[((long)(b * 16 + blockIdx.x)) * NPn + p] = make_float4(rs, rq, rm, 0.f);
    }

    // col partials: reduce across rt within wave (xor 8,16,32), then LDS across waves
#pragma unroll
    for (int m = 8; m < 64; m <<= 1)
#pragma unroll
        for (int t = 0; t < 8; t++) {
            cs[t] += __shfl_xor(cs[t], m);
            cq[t] += __shfl_xor(cq[t], m);
            cm[t] = fmaxf(cm[t], __shfl_xor(cm[t], m));
        }
    __shared__ float LS[4][64], LQ[4][64], LM[4][64];
    const int lane = tid & 63, wave = tid >> 6;
    if (lane < 8)
#pragma unroll
        for (int t = 0; t < 8; t++) {
            LS[wave][lane * 8 + t] = cs[t];
            LQ[wave][lane * 8 + t] = cq[t];
            LM[wave][lane * 8 + t] = cm[t];
        }
    __syncthreads();
    if (tid < 64) {
        float s0 = LS[0][tid] + LS[1][tid] + LS[2][tid] + LS[3][tid];
        float q0 = LQ[0][tid] + LQ[1][tid] + LQ[2][tid] + LQ[3][tid];
        float m0 = fmaxf(fmaxf(LM[0][tid], LM[1][tid]), fmaxf(LM[2][tid], LM[3][tid]));
        cp[((long)(b * 16 + blockIdx.y)) * NCn + c0 + tid] = make_float4(s0, q0, m0, 0.f);
    }
}

// ---------------------------------------------------------------------------
// Finalize stats: rows (B*NP entries, reduce 16 partials, N=NC) then cols
// (B*NC entries, reduce 16 partials, N=NP). thr = mean + std(ddof=1)/8.
// Also zeros d1/d2 (denominator accumulators).
// ---------------------------------------------------------------------------
__global__ __launch_bounds__(256) void stats_final(
    const float4* __restrict__ rp, const float4* __restrict__ cp,
    float2* __restrict__ row_tm, float2* __restrict__ col_tm,
    float* __restrict__ d1, float* __restrict__ d2)
{
    int idx = blockIdx.x * 256 + threadIdx.x;   // 0 .. B*NP + B*NC - 1
    if (idx < Bn * NPn) {
        int b = idx >> 12, p = idx & (NPn - 1);
        float s = 0.f, q = 0.f, m = -3.4e38f;
#pragma unroll
        for (int i = 0; i < 16; i++) {
            float4 v = rp[((long)(b * 16 + i)) * NPn + p];
            s += v.x; q += v.y; m = fmaxf(m, v.z);
        }
        float mean = s * (1.0f / NCn);
        float var = fmaxf((q - (float)NCn * mean * mean) * (1.0f / (NCn - 1)), 0.0f);
        row_tm[idx] = make_float2(mean + sqrtf(var) * 0.125f, m);
        d1[idx] = 0.f;
    } else {
        int cidx = idx - Bn * NPn;
        int b = cidx >> 10, c = cidx & (NCn - 1);
        float s = 0.f, q = 0.f, m = -3.4e38f;
#pragma unroll
        for (int i = 0; i < 16; i++) {
            float4 v = cp[((long)(b * 16 + i)) * NCn + c];
            s += v.x; q += v.y; m = fmaxf(m, v.z);
        }
        float mean = s * (1.0f / NPn);
        float var = fmaxf((q - (float)NPn * mean * mean) * (1.0f / (NPn - 1)), 0.0f);
        col_tm[cidx] = make_float2(mean + sqrtf(var) * 0.125f, m);
        d2[cidx] = 0.f;
    }
}

// ---------------------------------------------------------------------------
// Merged masked softmax: one read of S (bf16) produces
//   A1u[p][c] = (s>=thr_r[p]) ? exp(s-mx_r[p]) : 0    (row-major, unnormalized)
//   A2u[c][p] = (s>=thr_c[c]) ? exp(s-mx_c[c]) : 0    (transposed via LDS)
// d1[p], d2[c] accumulated via device atomics; normalization folded downstream.
// Tile: 256 rows x 64 cols. 256 threads.
// ---------------------------------------------------------------------------
__global__ __launch_bounds__(256) void softmax_merged(
    const bf16* __restrict__ S, const float2* __restrict__ row_tm,
    const float2* __restrict__ col_tm, float* __restrict__ d1,
    float* __restrict__ d2, bf16* __restrict__ A1u, bf16* __restrict__ A2u)
{
    const int b = blockIdx.z, c0 = blockIdx.x * 64, p0 = blockIdx.y * 256;
    const int tid = threadIdx.x;
    const int rt = tid >> 3;          // 0..31 row within pass
    const int ct = (tid & 7) * 8;     // col offset, 8 cols per thread

    __shared__ float T[64][265];      // transposed e2 staging
    __shared__ float dw2[4][64];      // per-wave col-denom partials

    float2 ctm[8];
#pragma unroll
    for (int t = 0; t < 8; t++) ctm[t] = col_tm[b * NCn + c0 + ct + t];

    float d2acc[8];
#pragma unroll
    for (int t = 0; t < 8; t++) d2acc[t] = 0.f;

#pragma unroll
    for (int pass = 0; pass < 8; pass++) {
        const int p = p0 + pass * 32 + rt;
        const float2 rtm = row_tm[b * NPn + p];
        const long sidx = ((long)(b * NPn + p)) * NCn + c0 + ct;
        short8 sv = *(const short8*)(S + sidx);
        bf16 o1[8] __attribute__((aligned(16)));
        float e1s = 0.f;
#pragma unroll
        for (int t = 0; t < 8; t++) {
            float x = b2f(sv[t]);
            float e1 = (x >= rtm.x) ? __expf(x - rtm.y) : 0.0f;
            o1[t] = __float2bfloat16(e1);
            e1s += e1;
            float e2 = (x >= ctm[t].x) ? __expf(x - ctm[t].y) : 0.0f;
            d2acc[t] += e2;
            T[ct + t][pass * 32 + rt] = e2;
        }
        *(short8*)(A1u + sidx) = *(const short8*)o1;
        e1s += __shfl_xor(e1s, 1);
        e1s += __shfl_xor(e1s, 2);
        e1s += __shfl_xor(e1s, 4);
        if ((tid & 7) == 0) atomicAdd(&d1[b * NPn + p], e1s);
    }

    // col denominators: reduce d2acc across rt within wave, then LDS
#pragma unroll
    for (int m = 8; m < 64; m <<= 1)
#pragma unroll
        for (int t = 0; t < 8; t++) d2acc[t] += __shfl_xor(d2acc[t], m);
    const int lane = tid & 63, wave = tid >> 6;
    if (lane < 8)
#pragma unroll
        for (int t = 0; t < 8; t++) dw2[wave][lane * 8 + t] = d2acc[t];
    __syncthreads();
    if (tid < 64)
        atomicAdd(&d2[b * NCn + c0 + tid],
                  dw2[0][tid] + dw2[1][tid] + dw2[2][tid] + dw2[3][tid]);

    // write A2u (transposed tile) from LDS
    const int c = tid >> 2, pb = (tid & 3) * 64;
    bf16* dst = A2u + ((long)(b * NCn + c0 + c)) * NPn + p0 + pb;
#pragma unroll
    for (int u = 0; u < 8; u++) {
        bf16 tmp[8] __attribute__((aligned(16)));
#pragma unroll
        for (int w = 0; w < 8; w++)
            tmp[w] = __float2bfloat16(T[c][pb + u * 8 + w]);
        *(short8*)(dst + u * 8) = *(const short8*)tmp;
    }
}

// ---------------------------------------------------------------------------
// Sum 4 split-K fp32 partials, scale row (b*NC+c) by 1/d2 -> bf16
// ---------------------------------------------------------------------------
__global__ __launch_bounds__(256) void reduce_scale_bf16(
    const float* __restrict__ Pp, const float* __restrict__ d2,
    bf16* __restrict__ out, long n4, long stride)
{
    long i = (long)blockIdx.x * 256 + threadIdx.x;
    if (i < n4) {
        float4 a = ((const float4*)Pp)[i];
#pragma unroll
        for (int s = 1; s < 4; s++) {
            float4 v = ((const float4*)(Pp + (long)s * stride))[i];
            a.x += v.x; a.y += v.y; a.z += v.z; a.w += v.w;
        }
        float inv = 1.0f / d2[i / (Dn / 4)];
        out[i * 4 + 0] = __float2bfloat16(a.x * inv);
        out[i * 4 + 1] = __float2bfloat16(a.y * inv);
        out[i * 4 + 2] = __float2bfloat16(a.z * inv);
        out[i * 4 + 3] = __float2bfloat16(a.w * inv);
    }
}

// ---------------------------------------------------------------------------
// fp32 [R x C] -> bf16 row-major copy AND bf16 [C x R] transpose, batched z.
// ---------------------------------------------------------------------------
__global__ __launch_bounds__(256) void cvt_both(
    const float* __restrict__ in, bf16* __restrict__ out_rm,
    bf16* __restrict__ out_t, int R, int C)
{
    __shared__ float tile[32][33];
    const long boff = (long)blockIdx.z * (long)R * C;
    in += boff; out_rm += boff; out_t += boff;
    const int c0 = blockIdx.x * 32, r0 = blockIdx.y * 32;
    const int tx = threadIdx.x, ty = threadIdx.y;
#pragma unroll
    for (int i = ty; i < 32; i += 8) {
        float x = in[(long)(r0 + i) * C + c0 + tx];
        tile[i][tx] = x;
        out_rm[(long)(r0 + i) * C + c0 + tx] = __float2bfloat16(x);
    }
    __syncthreads();
#pragma unroll
    for (int i = ty; i < 32; i += 8)
        out_t[(long)(c0 + i) * R + r0 + tx] = __float2bfloat16(tile[tx][i]);
}

// ---------------------------------------------------------------------------
extern "C" void kernel_launch(void* const* d_in, const int* in_sizes, int n_in,
                              void* d_out, int out_size, void* d_ws, size_t ws_size,
                              hipStream_t stream)
{
    const float* Xp = (const float*)d_in[0];  // [4,4096,512]
    const float* Xc = (const float*)d_in[1];  // [4,1024,512]
    float* out = (float*)d_out;               // [4,4096,1024]

    constexpr int B = Bn, NP = NPn, NC = NCn, D = Dn;
    constexpr float SCALE = 0.044194173824159216f;  // 1/sqrt(512)

    // workspace layout (bytes), ~164 MB
    char* ws = (char*)d_ws;
    bf16*   Qp     = (bf16*)(ws);                   // 16.78 MB [B,NP,D]
    bf16*   Kc     = (bf16*)(ws + 16777216);        //  4.19 MB [B,NC,D]
    bf16*   KcT    = (bf16*)(ws + 20971520);        //  4.19 MB [B,D,NC]
    bf16*   XpT    = (bf16*)(ws + 25165824);        // 16.78 MB [B,D,NP]
    bf16*   S      = (bf16*)(ws + 41943040);        // 33.55 MB [B,NP,NC]; later Hp overlays
    bf16*   A1u    = (bf16*)(ws + 75497472);        // 33.55 MB [B,NP,NC]
    bf16*   A2u    = (bf16*)(ws + 109051904);       // 33.55 MB [B,NC,NP]; rp/cp overlay pre-softmax
    bf16*   H1u    = (bf16*)(ws + 142606336);       // 16.78 MB [B,NP,D]
    bf16*   H2     = (bf16*)(ws + 159383552);       //  4.19 MB [B,NC,D]
    float2* row_tm = (float2*)(ws + 163577856);     // 128 KB  [B*NP]
    float2* col_tm = (float2*)(ws + 163708928);     //  32 KB  [B*NC]
    float*  d1     = (float*)(ws + 163741696);      //  64 KB  [B*NP]
    float*  d2     = (float*)(ws + 163807232);      //  16 KB  [B*NC]
    // stat partials overlay A2u (dead until softmax_merged; consumed by stats_final)
    float4* rp     = (float4*)A2u;                  //  4.19 MB [B*16,NP]
    float4* cp     = (float4*)(ws + 109051904 + 4194304);  // 1.05 MB [B*16,NC]
    float*  Hp     = (float*)S;                     // split-K partials [4][B,NC,D] fp32 (S dead)

    // 1-2: convert + transpose inputs (one read of fp32 each)
    cvt_both<<<dim3(D / 32, NP / 32, B), dim3(32, 8), 0, stream>>>(Xp, Qp, XpT, NP, D);
    cvt_both<<<dim3(D / 32, NC / 32, B), dim3(32, 8), 0, stream>>>(Xc, Kc, KcT, NC, D);

    // 3: S = Qp*Kc^T*scale (bf16)
    gemm_bt<bf16, false><<<dim3(NC / 128, NP / 128, B), dim3(256), 0, stream>>>(
        Qp, Kc, S, NP, NC, D, (long)NP * D, (long)NC * D, (long)NP * NC,
        SCALE, B, 1, nullptr);
    // 4: one-pass row+col stat partials from S
    stats_both<<<dim3(NC / 64, NP / 256, B), dim3(256), 0, stream>>>(S, rp, cp);
    // 5: finalize thr/max; zero denoms
    stats_final<<<dim3((B * NP + B * NC) / 256), dim3(256), 0, stream>>>(
        rp, cp, row_tm, col_tm, d1, d2);
    // 6: merged softmax -> A1u (row-major) + A2u (transposed), denoms via atomics
    softmax_merged<<<dim3(NC / 64, NP / 256, B), dim3(256), 0, stream>>>(
        S, row_tm, col_tm, d1, d2, A1u, A2u);
    // 7: H1u = A1u * Kc            [B,NP,D] bf16 (unnormalized; 1/d1 folded into step 10)
    gemm_bt<bf16, false><<<dim3(D / 128, NP / 128, B), dim3(256), 0, stream>>>(
        A1u, KcT, H1u, NP, D, NC, (long)NP * NC, (long)D * NC, (long)NP * D,
        1.0f, B, 1, nullptr);
    // 8: Hp = A2u * Xp partials    [4][B,NC,D] fp32, 4-way split-K
    gemm_bt<float, false><<<dim3(D / 128, NC / 128, 4 * B), dim3(256), 0, stream>>>(
        A2u, XpT, Hp, NC, D, NP, (long)NC * NP, (long)D * NP, (long)NC * D,
        1.0f, B, 4, nullptr);
    // 9: H2 = sum(Hp) / d2 -> bf16
    {
        long n = (long)B * NC * D;
        reduce_scale_bf16<<<dim3((n / 4 + 255) / 256), dim3(256), 0, stream>>>(
            Hp, d2, H2, n / 4, n);
    }
    // 10: out = diag(1/d1) * H1u * H2^T   [B,NP,NC] fp32
    gemm_bt<float, true><<<dim3(NC / 128, NP / 128, B), dim3(256), 0, stream>>>(
        H1u, H2, out, NP, NC, D, (long)NP * D, (long)NC * D, (long)NP * NC,
        1.0f, B, 1, d1);
}